// Round 1
// baseline (635.380 us; speedup 1.0000x reference)
//
#include <hip/hip_runtime.h>
#include <hip/hip_bf16.h>

typedef __attribute__((ext_vector_type(4))) float f32x4;
typedef __attribute__((ext_vector_type(8))) short bf16x8;
typedef __attribute__((ext_vector_type(4))) unsigned short u16x4;
typedef __attribute__((ext_vector_type(8))) unsigned short u16x8;

#define MFMA16(a, b, c) __builtin_amdgcn_mfma_f32_16x16x32_bf16((a), (b), (c), 0, 0, 0)

static __device__ __forceinline__ unsigned short f2bf(float f) {
    union { float f; unsigned int u; } v; v.f = f;
    unsigned int r = v.u + 0x7FFFu + ((v.u >> 16) & 1u);  // RNE
    return (unsigned short)(r >> 16);
}

// ---------------------------------------------------------------------------
// GEMM: Out[4096 x 1024] = A[4096 x 1024] * W[1024 x 1024] + bias
// A is fp32 (A_BF16=false) or bf16 (true); Out is bf16 (OUT_BF16=true) or fp32.
// 128x128 tile, 4 waves (2x2), each wave 64x64 = 4x4 frags of 16x16, BK=32.
// ---------------------------------------------------------------------------
template <bool A_BF16, bool OUT_BF16>
__global__ __launch_bounds__(256, 2) void gemm_kernel(
    const void* __restrict__ Av, const float* __restrict__ W,
    const float* __restrict__ bias, void* __restrict__ Outv) {
    __shared__ __align__(16) unsigned short As[128][40];  // [row][k], +8 pad
    __shared__ __align__(16) unsigned short Bs[128][40];  // [col][k] (transposed)

    const int t = threadIdx.x;
    const int bm = blockIdx.y * 128;
    const int bn = blockIdx.x * 128;
    const int w = t >> 6, lane = t & 63;
    const int wr = w >> 1, wc = w & 1;
    const int g = lane >> 4, r15 = lane & 15;

    f32x4 acc[4][4];
#pragma unroll
    for (int m = 0; m < 4; ++m)
#pragma unroll
        for (int n = 0; n < 4; ++n) acc[m][n] = (f32x4){0.f, 0.f, 0.f, 0.f};

    const float* Af = (const float*)Av;
    const unsigned short* Ab = (const unsigned short*)Av;

    for (int kt = 0; kt < 1024; kt += 32) {
        __syncthreads();
        // ---- stage A tile: rows bm..bm+127, k cols kt..kt+31
#pragma unroll
        for (int i = 0; i < 4; ++i) {
            int row = (t >> 3) + i * 32;
            int c4 = (t & 7) * 4;
            if (A_BF16) {
                u16x4 v = *(const u16x4*)&Ab[(size_t)(bm + row) * 1024 + kt + c4];
                *(u16x4*)&As[row][c4] = v;
            } else {
                f32x4 v = *(const f32x4*)&Af[(size_t)(bm + row) * 1024 + kt + c4];
                u16x4 o;
                o[0] = f2bf(v[0]); o[1] = f2bf(v[1]);
                o[2] = f2bf(v[2]); o[3] = f2bf(v[3]);
                *(u16x4*)&As[row][c4] = o;
            }
        }
        // ---- stage B tile transposed: W rows kt..kt+31, cols bn..bn+127
#pragma unroll
        for (int i = 0; i < 4; ++i) {
            int k = (t >> 5) + i * 8;
            int c4 = (t & 31) * 4;
            f32x4 v = *(const f32x4*)&W[(size_t)(kt + k) * 1024 + bn + c4];
#pragma unroll
            for (int j = 0; j < 4; ++j) Bs[c4 + j][k] = f2bf(v[j]);
        }
        __syncthreads();
        // ---- compute
        bf16x8 af[4], bfr[4];
#pragma unroll
        for (int m = 0; m < 4; ++m)
            af[m] = *(const bf16x8*)&As[wr * 64 + m * 16 + r15][g * 8];
#pragma unroll
        for (int n = 0; n < 4; ++n)
            bfr[n] = *(const bf16x8*)&Bs[wc * 64 + n * 16 + r15][g * 8];
#pragma unroll
        for (int m = 0; m < 4; ++m)
#pragma unroll
            for (int n = 0; n < 4; ++n)
                acc[m][n] = MFMA16(af[m], bfr[n], acc[m][n]);
    }

    // ---- epilogue: bias add + store (C/D layout: row=(g*4+r), col=r15)
    float* Of = (float*)Outv;
    unsigned short* Ob = (unsigned short*)Outv;
#pragma unroll
    for (int n = 0; n < 4; ++n) {
        int col = bn + wc * 64 + n * 16 + r15;
        float bv = bias[col];
#pragma unroll
        for (int m = 0; m < 4; ++m) {
#pragma unroll
            for (int r = 0; r < 4; ++r) {
                int row = bm + wr * 64 + m * 16 + g * 4 + r;
                float val = acc[m][n][r] + bv;
                if (OUT_BF16)
                    Ob[(size_t)row * 1024 + col] = f2bf(val);
                else
                    Of[(size_t)row * 1024 + col] = val;
            }
        }
    }
}

// ---------------------------------------------------------------------------
// Flash attention: per block one (b,h), 64 q-rows (4 waves x 16 rows).
// KV tiles of 64; online softmax; bf16 in (ws), bf16 out (ws).
// ---------------------------------------------------------------------------
__global__ __launch_bounds__(256, 2) void attn_kernel(
    const unsigned short* __restrict__ Q, const unsigned short* __restrict__ K,
    const unsigned short* __restrict__ V, unsigned short* __restrict__ O) {
    __shared__ __align__(16) unsigned short Ks[64][72];      // [key][d]
    __shared__ __align__(16) unsigned short Vs[64][72];      // [d][key] (transposed)
    __shared__ __align__(16) unsigned short Ps[4][16][72];   // per-wave P strip

    const int t = threadIdx.x;
    const int w = t >> 6, lane = t & 63;
    const int g = lane >> 4, r15 = lane & 15;
    const int b = blockIdx.y >> 4, h = blockIdx.y & 15;
    const int q0 = blockIdx.x * 64;

    // Q fragments (A operand, rows = r15 within this wave's 16-row strip)
    const size_t qbase = (size_t)(b * 1024 + q0 + w * 16 + r15) * 1024 + h * 64;
    bf16x8 qf0 = *(const bf16x8*)&Q[qbase + g * 8];
    bf16x8 qf1 = *(const bf16x8*)&Q[qbase + 32 + g * 8];

    f32x4 o[4];
#pragma unroll
    for (int c = 0; c < 4; ++c) o[c] = (f32x4){0.f, 0.f, 0.f, 0.f};
    float m[4] = {-1e30f, -1e30f, -1e30f, -1e30f};
    float l[4] = {0.f, 0.f, 0.f, 0.f};

    for (int kt = 0; kt < 1024; kt += 64) {
        __syncthreads();
        // ---- stage K (as-is) and V (transposed)
#pragma unroll
        for (int i = 0; i < 2; ++i) {
            int key = (t >> 3) + i * 32;
            int d8 = (t & 7) * 8;
            size_t src = (size_t)(b * 1024 + kt + key) * 1024 + h * 64 + d8;
            u16x8 kv = *(const u16x8*)&K[src];
            *(u16x8*)&Ks[key][d8] = kv;
            u16x8 vv = *(const u16x8*)&V[src];
#pragma unroll
            for (int j = 0; j < 8; ++j) Vs[d8 + j][key] = vv[j];
        }
        __syncthreads();

        // ---- scores: S = Q * K^T  (16 x 64 per wave)
        f32x4 s[4];
#pragma unroll
        for (int c = 0; c < 4; ++c) {
            bf16x8 kf0 = *(const bf16x8*)&Ks[c * 16 + r15][g * 8];
            bf16x8 kf1 = *(const bf16x8*)&Ks[c * 16 + r15][32 + g * 8];
            f32x4 z = (f32x4){0.f, 0.f, 0.f, 0.f};
            s[c] = MFMA16(qf0, kf0, z);
            s[c] = MFMA16(qf1, kf1, s[c]);
        }
#pragma unroll
        for (int c = 0; c < 4; ++c)
#pragma unroll
            for (int r = 0; r < 4; ++r) s[c][r] *= 0.125f;  // 1/sqrt(64)

        // ---- online softmax (row r lives on 16 lanes sharing g)
        float mt[4];
#pragma unroll
        for (int r = 0; r < 4; ++r) {
            mt[r] = fmaxf(fmaxf(s[0][r], s[1][r]), fmaxf(s[2][r], s[3][r]));
#pragma unroll
            for (int mk = 1; mk <= 8; mk <<= 1)
                mt[r] = fmaxf(mt[r], __shfl_xor(mt[r], mk));
        }
        float sf[4], rs[4], p[4][4];
#pragma unroll
        for (int r = 0; r < 4; ++r) {
            float mn = fmaxf(m[r], mt[r]);
            sf[r] = __expf(m[r] - mn);
            m[r] = mn;
            rs[r] = 0.f;
        }
#pragma unroll
        for (int c = 0; c < 4; ++c)
#pragma unroll
            for (int r = 0; r < 4; ++r) {
                float pv = __expf(s[c][r] - m[r]);
                p[c][r] = pv;
                rs[r] += pv;
            }
#pragma unroll
        for (int r = 0; r < 4; ++r) {
#pragma unroll
            for (int mk = 1; mk <= 8; mk <<= 1) rs[r] += __shfl_xor(rs[r], mk);
            l[r] = l[r] * sf[r] + rs[r];
        }
#pragma unroll
        for (int c = 0; c < 4; ++c)
#pragma unroll
            for (int r = 0; r < 4; ++r) o[c][r] *= sf[r];

        // ---- P -> LDS (C/D coords) then reload as A operand
#pragma unroll
        for (int c = 0; c < 4; ++c)
#pragma unroll
            for (int r = 0; r < 4; ++r)
                Ps[w][g * 4 + r][c * 16 + r15] = f2bf(p[c][r]);
        __syncthreads();
        bf16x8 pa0 = *(const bf16x8*)&Ps[w][r15][g * 8];
        bf16x8 pa1 = *(const bf16x8*)&Ps[w][r15][32 + g * 8];
#pragma unroll
        for (int c = 0; c < 4; ++c) {
            bf16x8 vf0 = *(const bf16x8*)&Vs[c * 16 + r15][g * 8];
            bf16x8 vf1 = *(const bf16x8*)&Vs[c * 16 + r15][32 + g * 8];
            o[c] = MFMA16(pa0, vf0, o[c]);
            o[c] = MFMA16(pa1, vf1, o[c]);
        }
    }

    // ---- epilogue: divide by running sum, store bf16
#pragma unroll
    for (int r = 0; r < 4; ++r) {
        float inv = 1.0f / l[r];
        size_t row = (size_t)(b * 1024 + q0 + w * 16 + g * 4 + r);
#pragma unroll
        for (int c = 0; c < 4; ++c)
            O[row * 1024 + h * 64 + c * 16 + r15] = f2bf(o[c][r] * inv);
    }
}

extern "C" void kernel_launch(void* const* d_in, const int* in_sizes, int n_in,
                              void* d_out, int out_size, void* d_ws, size_t ws_size,
                              hipStream_t stream) {
    const float* q  = (const float*)d_in[0];
    const float* k  = (const float*)d_in[1];
    const float* v  = (const float*)d_in[2];
    const float* Wq = (const float*)d_in[3];
    const float* bq = (const float*)d_in[4];
    const float* Wk = (const float*)d_in[5];
    const float* bk = (const float*)d_in[6];
    const float* Wv = (const float*)d_in[7];
    const float* bv = (const float*)d_in[8];
    const float* Wo = (const float*)d_in[9];
    const float* bo = (const float*)d_in[10];

    const size_t NE = (size_t)4096 * 1024;
    unsigned short* Qb = (unsigned short*)d_ws;
    unsigned short* Kb = Qb + NE;
    unsigned short* Vb = Kb + NE;
    unsigned short* Ob = Vb + NE;  // total ws use: 32 MB

    dim3 gg(8, 32), bt(256, 1, 1);
    gemm_kernel<false, true><<<gg, bt, 0, stream>>>(q, Wq, bq, Qb);
    gemm_kernel<false, true><<<gg, bt, 0, stream>>>(k, Wk, bk, Kb);
    gemm_kernel<false, true><<<gg, bt, 0, stream>>>(v, Wv, bv, Vb);
    attn_kernel<<<dim3(16, 64), bt, 0, stream>>>(Qb, Kb, Vb, Ob);
    gemm_kernel<true, false><<<gg, bt, 0, stream>>>(Ob, Wo, bo, d_out);
}

// Round 2
// 268.875 us; speedup vs baseline: 2.3631x; 2.3631x over previous
//
#include <hip/hip_runtime.h>
#include <hip/hip_bf16.h>

typedef __attribute__((ext_vector_type(4))) float f32x4;
typedef __attribute__((ext_vector_type(8))) short bf16x8;
typedef __attribute__((ext_vector_type(4))) unsigned short u16x4;
typedef __attribute__((ext_vector_type(8))) unsigned short u16x8;

#define MFMA16(a, b, c) __builtin_amdgcn_mfma_f32_16x16x32_bf16((a), (b), (c), 0, 0, 0)

static __device__ __forceinline__ unsigned short f2bf(float f) {
    union { float f; unsigned int u; } v; v.f = f;
    unsigned int r = v.u + 0x7FFFu + ((v.u >> 16) & 1u);  // RNE
    return (unsigned short)(r >> 16);
}

static __device__ __forceinline__ void gload_lds16(const void* g, void* l) {
    __builtin_amdgcn_global_load_lds(
        (const __attribute__((address_space(1))) void*)g,
        (__attribute__((address_space(3))) void*)l, 16, 0, 0);
}

// ---------------------------------------------------------------------------
// convert_act: fp32 -> bf16, 8 elems/thread. blockIdx.y selects tensor.
// ---------------------------------------------------------------------------
__global__ __launch_bounds__(256) void convert_act(
    const float* __restrict__ q, const float* __restrict__ k,
    const float* __restrict__ v, unsigned short* __restrict__ qc,
    unsigned short* __restrict__ kc, unsigned short* __restrict__ vc) {
    const float* src = blockIdx.y == 0 ? q : (blockIdx.y == 1 ? k : v);
    unsigned short* dst = blockIdx.y == 0 ? qc : (blockIdx.y == 1 ? kc : vc);
    size_t off = ((size_t)blockIdx.x * 256 + threadIdx.x) * 8;
    f32x4 a = *(const f32x4*)&src[off];
    f32x4 b = *(const f32x4*)&src[off + 4];
    u16x8 o;
    o[0] = f2bf(a[0]); o[1] = f2bf(a[1]); o[2] = f2bf(a[2]); o[3] = f2bf(a[3]);
    o[4] = f2bf(b[0]); o[5] = f2bf(b[1]); o[6] = f2bf(b[2]); o[7] = f2bf(b[3]);
    *(u16x8*)&dst[off] = o;
}

// ---------------------------------------------------------------------------
// transpose_w: W[k][n] fp32 -> Wt[n][k] bf16. 64x64 tiles, z = matrix 0..3.
// ---------------------------------------------------------------------------
__global__ __launch_bounds__(256) void transpose_w(
    const float* __restrict__ Wq, const float* __restrict__ Wk,
    const float* __restrict__ Wv, const float* __restrict__ Wo,
    unsigned short* __restrict__ Wt_all, unsigned short* __restrict__ Wot) {
    __shared__ unsigned short T[64][65];
    const int z = blockIdx.z;
    const float* W = z == 0 ? Wq : (z == 1 ? Wk : (z == 2 ? Wv : Wo));
    unsigned short* Wt = z < 3 ? (Wt_all + (size_t)z * 1024 * 1024) : Wot;
    const int k0 = blockIdx.y * 64, n0 = blockIdx.x * 64;
    const int t = threadIdx.x;
    const int rl = t >> 4, c4 = (t & 15) * 4;
#pragma unroll
    for (int i = 0; i < 4; ++i) {
        f32x4 v = *(const f32x4*)&W[(size_t)(k0 + rl + 16 * i) * 1024 + n0 + c4];
#pragma unroll
        for (int j = 0; j < 4; ++j) T[rl + 16 * i][c4 + j] = f2bf(v[j]);
    }
    __syncthreads();
#pragma unroll
    for (int i = 0; i < 4; ++i) {
        u16x4 o;
#pragma unroll
        for (int j = 0; j < 4; ++j) o[j] = T[c4 + j][rl + 16 * i];
        *(u16x4*)&Wt[(size_t)(n0 + rl + 16 * i) * 1024 + k0 + c4] = o;
    }
}

// ---------------------------------------------------------------------------
// gemm_fast: Out[.. x ..] = A[M x 1024](bf16) * Wt[N x 1024]^T(bf16) + bias
// m97 structure: 128x128 tile, BK=32, 4 waves (2x2), global_load_lds x16,
// linear LDS, ds_read_b128 fragments. A/bias selected per 1024-col group.
// ---------------------------------------------------------------------------
template <bool OUT_BF16>
__global__ __launch_bounds__(256, 2) void gemm_fast(
    const unsigned short* __restrict__ A0, const unsigned short* __restrict__ A1,
    const unsigned short* __restrict__ A2, const unsigned short* __restrict__ Wt,
    const float* __restrict__ b0, const float* __restrict__ b1,
    const float* __restrict__ b2, void* __restrict__ Outv, int ldo) {
    __shared__ __align__(16) unsigned short As[128 * 32];
    __shared__ __align__(16) unsigned short Bs[128 * 32];

    const int t = threadIdx.x;
    const int w = t >> 6, lane = t & 63;
    const int wr = w >> 1, wc = w & 1;
    const int g = lane >> 4, r15 = lane & 15;
    const int bm = blockIdx.y * 128;
    const int bn = blockIdx.x * 128;
    const int msel = bn >> 10;
    const unsigned short* A = msel == 0 ? A0 : (msel == 1 ? A1 : A2);
    const float* bias = msel == 0 ? b0 : (msel == 1 ? b1 : b2);
    const int l4 = lane >> 2, c8 = (lane & 3) * 8;

    f32x4 acc[4][4];
#pragma unroll
    for (int m = 0; m < 4; ++m)
#pragma unroll
        for (int n = 0; n < 4; ++n) acc[m][n] = (f32x4){0.f, 0.f, 0.f, 0.f};

    for (int kt = 0; kt < 1024; kt += 32) {
        __syncthreads();
        gload_lds16(&A[(size_t)(bm + 16 * w + l4) * 1024 + kt + c8], &As[w * 512]);
        gload_lds16(&A[(size_t)(bm + 16 * (w + 4) + l4) * 1024 + kt + c8], &As[(w + 4) * 512]);
        gload_lds16(&Wt[(size_t)(bn + 16 * w + l4) * 1024 + kt + c8], &Bs[w * 512]);
        gload_lds16(&Wt[(size_t)(bn + 16 * (w + 4) + l4) * 1024 + kt + c8], &Bs[(w + 4) * 512]);
        __syncthreads();
        bf16x8 af[4], bfr[4];
#pragma unroll
        for (int m = 0; m < 4; ++m)
            af[m] = *(const bf16x8*)&As[(wr * 64 + m * 16 + r15) * 32 + g * 8];
#pragma unroll
        for (int n = 0; n < 4; ++n)
            bfr[n] = *(const bf16x8*)&Bs[(wc * 64 + n * 16 + r15) * 32 + g * 8];
#pragma unroll
        for (int m = 0; m < 4; ++m)
#pragma unroll
            for (int n = 0; n < 4; ++n)
                acc[m][n] = MFMA16(af[m], bfr[n], acc[m][n]);
    }

    float* Of = (float*)Outv;
    unsigned short* Ob = (unsigned short*)Outv;
#pragma unroll
    for (int n = 0; n < 4; ++n) {
        int col = bn + wc * 64 + n * 16 + r15;
        float bv = bias[col & 1023];
#pragma unroll
        for (int m = 0; m < 4; ++m) {
#pragma unroll
            for (int r = 0; r < 4; ++r) {
                int row = bm + wr * 64 + m * 16 + g * 4 + r;
                float val = acc[m][n][r] + bv;
                if (OUT_BF16)
                    Ob[(size_t)row * ldo + col] = f2bf(val);
                else
                    Of[(size_t)row * ldo + col] = val;
            }
        }
    }
}

// ---------------------------------------------------------------------------
// Legacy fp32-A GEMM (fallback path if ws too small): round-1 kernel.
// ---------------------------------------------------------------------------
template <bool A_BF16, bool OUT_BF16>
__global__ __launch_bounds__(256, 2) void gemm_kernel(
    const void* __restrict__ Av, const float* __restrict__ W,
    const float* __restrict__ bias, void* __restrict__ Outv) {
    __shared__ __align__(16) unsigned short As[128][40];
    __shared__ __align__(16) unsigned short Bs[128][40];

    const int t = threadIdx.x;
    const int bm = blockIdx.y * 128;
    const int bn = blockIdx.x * 128;
    const int w = t >> 6, lane = t & 63;
    const int wr = w >> 1, wc = w & 1;
    const int g = lane >> 4, r15 = lane & 15;

    f32x4 acc[4][4];
#pragma unroll
    for (int m = 0; m < 4; ++m)
#pragma unroll
        for (int n = 0; n < 4; ++n) acc[m][n] = (f32x4){0.f, 0.f, 0.f, 0.f};

    const float* Af = (const float*)Av;
    const unsigned short* Ab = (const unsigned short*)Av;

    for (int kt = 0; kt < 1024; kt += 32) {
        __syncthreads();
#pragma unroll
        for (int i = 0; i < 4; ++i) {
            int row = (t >> 3) + i * 32;
            int c4 = (t & 7) * 4;
            if (A_BF16) {
                u16x4 v = *(const u16x4*)&Ab[(size_t)(bm + row) * 1024 + kt + c4];
                *(u16x4*)&As[row][c4] = v;
            } else {
                f32x4 v = *(const f32x4*)&Af[(size_t)(bm + row) * 1024 + kt + c4];
                u16x4 o;
                o[0] = f2bf(v[0]); o[1] = f2bf(v[1]);
                o[2] = f2bf(v[2]); o[3] = f2bf(v[3]);
                *(u16x4*)&As[row][c4] = o;
            }
        }
#pragma unroll
        for (int i = 0; i < 4; ++i) {
            int k = (t >> 5) + i * 8;
            int c4 = (t & 31) * 4;
            f32x4 v = *(const f32x4*)&W[(size_t)(kt + k) * 1024 + bn + c4];
#pragma unroll
            for (int j = 0; j < 4; ++j) Bs[c4 + j][k] = f2bf(v[j]);
        }
        __syncthreads();
        bf16x8 af[4], bfr[4];
#pragma unroll
        for (int m = 0; m < 4; ++m)
            af[m] = *(const bf16x8*)&As[wr * 64 + m * 16 + r15][g * 8];
#pragma unroll
        for (int n = 0; n < 4; ++n)
            bfr[n] = *(const bf16x8*)&Bs[wc * 64 + n * 16 + r15][g * 8];
#pragma unroll
        for (int m = 0; m < 4; ++m)
#pragma unroll
            for (int n = 0; n < 4; ++n)
                acc[m][n] = MFMA16(af[m], bfr[n], acc[m][n]);
    }

    float* Of = (float*)Outv;
    unsigned short* Ob = (unsigned short*)Outv;
#pragma unroll
    for (int n = 0; n < 4; ++n) {
        int col = bn + wc * 64 + n * 16 + r15;
        float bv = bias[col];
#pragma unroll
        for (int m = 0; m < 4; ++m) {
#pragma unroll
            for (int r = 0; r < 4; ++r) {
                int row = bm + wr * 64 + m * 16 + g * 4 + r;
                float val = acc[m][n][r] + bv;
                if (OUT_BF16)
                    Ob[(size_t)row * 1024 + col] = f2bf(val);
                else
                    Of[(size_t)row * 1024 + col] = val;
            }
        }
    }
}

// ---------------------------------------------------------------------------
// Flash attention: one (b,h) per blockIdx.y, 64 q-rows (4 waves x 16 rows).
// Q/K/V read with leading dim `ld` (3072 for fused QKV buffer, 1024 legacy).
// ---------------------------------------------------------------------------
__global__ __launch_bounds__(256, 2) void attn_kernel(
    const unsigned short* __restrict__ Q, const unsigned short* __restrict__ K,
    const unsigned short* __restrict__ V, unsigned short* __restrict__ O, int ld) {
    __shared__ __align__(16) unsigned short Ks[64][72];
    __shared__ __align__(16) unsigned short Vs[64][72];
    __shared__ __align__(16) unsigned short Ps[4][16][72];

    const int t = threadIdx.x;
    const int w = t >> 6, lane = t & 63;
    const int g = lane >> 4, r15 = lane & 15;
    const int b = blockIdx.y >> 4, h = blockIdx.y & 15;
    const int q0 = blockIdx.x * 64;

    const size_t qbase = (size_t)(b * 1024 + q0 + w * 16 + r15) * ld + h * 64;
    bf16x8 qf0 = *(const bf16x8*)&Q[qbase + g * 8];
    bf16x8 qf1 = *(const bf16x8*)&Q[qbase + 32 + g * 8];

    f32x4 o[4];
#pragma unroll
    for (int c = 0; c < 4; ++c) o[c] = (f32x4){0.f, 0.f, 0.f, 0.f};
    float m[4] = {-1e30f, -1e30f, -1e30f, -1e30f};
    float l[4] = {0.f, 0.f, 0.f, 0.f};

    for (int kt = 0; kt < 1024; kt += 64) {
        __syncthreads();
#pragma unroll
        for (int i = 0; i < 2; ++i) {
            int key = (t >> 3) + i * 32;
            int d8 = (t & 7) * 8;
            size_t src = (size_t)(b * 1024 + kt + key) * ld + h * 64 + d8;
            u16x8 kv = *(const u16x8*)&K[src];
            *(u16x8*)&Ks[key][d8] = kv;
            u16x8 vv = *(const u16x8*)&V[src];
#pragma unroll
            for (int j = 0; j < 8; ++j) Vs[d8 + j][key] = vv[j];
        }
        __syncthreads();

        f32x4 s[4];
#pragma unroll
        for (int c = 0; c < 4; ++c) {
            bf16x8 kf0 = *(const bf16x8*)&Ks[c * 16 + r15][g * 8];
            bf16x8 kf1 = *(const bf16x8*)&Ks[c * 16 + r15][32 + g * 8];
            f32x4 z = (f32x4){0.f, 0.f, 0.f, 0.f};
            s[c] = MFMA16(qf0, kf0, z);
            s[c] = MFMA16(qf1, kf1, s[c]);
        }
#pragma unroll
        for (int c = 0; c < 4; ++c)
#pragma unroll
            for (int r = 0; r < 4; ++r) s[c][r] *= 0.125f;

        float mt[4];
#pragma unroll
        for (int r = 0; r < 4; ++r) {
            mt[r] = fmaxf(fmaxf(s[0][r], s[1][r]), fmaxf(s[2][r], s[3][r]));
#pragma unroll
            for (int mk = 1; mk <= 8; mk <<= 1)
                mt[r] = fmaxf(mt[r], __shfl_xor(mt[r], mk));
        }
        float sf[4], rs[4], p[4][4];
#pragma unroll
        for (int r = 0; r < 4; ++r) {
            float mn = fmaxf(m[r], mt[r]);
            sf[r] = __expf(m[r] - mn);
            m[r] = mn;
            rs[r] = 0.f;
        }
#pragma unroll
        for (int c = 0; c < 4; ++c)
#pragma unroll
            for (int r = 0; r < 4; ++r) {
                float pv = __expf(s[c][r] - m[r]);
                p[c][r] = pv;
                rs[r] += pv;
            }
#pragma unroll
        for (int r = 0; r < 4; ++r) {
#pragma unroll
            for (int mk = 1; mk <= 8; mk <<= 1) rs[r] += __shfl_xor(rs[r], mk);
            l[r] = l[r] * sf[r] + rs[r];
        }
#pragma unroll
        for (int c = 0; c < 4; ++c)
#pragma unroll
            for (int r = 0; r < 4; ++r) o[c][r] *= sf[r];

#pragma unroll
        for (int c = 0; c < 4; ++c)
#pragma unroll
            for (int r = 0; r < 4; ++r)
                Ps[w][g * 4 + r][c * 16 + r15] = f2bf(p[c][r]);
        __syncthreads();
        bf16x8 pa0 = *(const bf16x8*)&Ps[w][r15][g * 8];
        bf16x8 pa1 = *(const bf16x8*)&Ps[w][r15][32 + g * 8];
#pragma unroll
        for (int c = 0; c < 4; ++c) {
            bf16x8 vf0 = *(const bf16x8*)&Vs[c * 16 + r15][g * 8];
            bf16x8 vf1 = *(const bf16x8*)&Vs[c * 16 + r15][32 + g * 8];
            o[c] = MFMA16(pa0, vf0, o[c]);
            o[c] = MFMA16(pa1, vf1, o[c]);
        }
    }

#pragma unroll
    for (int r = 0; r < 4; ++r) {
        float inv = 1.0f / l[r];
        size_t row = (size_t)(b * 1024 + q0 + w * 16 + g * 4 + r);
#pragma unroll
        for (int c = 0; c < 4; ++c)
            O[row * 1024 + h * 64 + c * 16 + r15] = f2bf(o[c][r] * inv);
    }
}

extern "C" void kernel_launch(void* const* d_in, const int* in_sizes, int n_in,
                              void* d_out, int out_size, void* d_ws, size_t ws_size,
                              hipStream_t stream) {
    const float* q  = (const float*)d_in[0];
    const float* k  = (const float*)d_in[1];
    const float* v  = (const float*)d_in[2];
    const float* Wq = (const float*)d_in[3];
    const float* bq = (const float*)d_in[4];
    const float* Wk = (const float*)d_in[5];
    const float* bk = (const float*)d_in[6];
    const float* Wv = (const float*)d_in[7];
    const float* bv = (const float*)d_in[8];
    const float* Wo = (const float*)d_in[9];
    const float* bo = (const float*)d_in[10];

    const size_t M1 = (size_t)1024 * 1024;       // 1M elems
    const size_t NEED = 28 * M1 * sizeof(unsigned short);  // 56 MB

    dim3 bt(256, 1, 1);
    if (ws_size >= NEED) {
        unsigned short* qc  = (unsigned short*)d_ws;       // 4M elems
        unsigned short* kc  = qc + 4 * M1;
        unsigned short* vc  = kc + 4 * M1;
        unsigned short* Wt  = vc + 4 * M1;                 // 3M elems [3072][1024]
        unsigned short* Wot = Wt + 3 * M1;                 // 1M elems
        unsigned short* QKV = Wot + M1;                    // 12M elems [4096][3072]
        unsigned short* Ob  = qc;                          // alias (qc dead by then)

        convert_act<<<dim3(2048, 3), bt, 0, stream>>>(q, k, v, qc, kc, vc);
        transpose_w<<<dim3(16, 16, 4), bt, 0, stream>>>(Wq, Wk, Wv, Wo, Wt, Wot);
        gemm_fast<true><<<dim3(24, 32), bt, 0, stream>>>(qc, kc, vc, Wt, bq, bk, bv, QKV, 3072);
        attn_kernel<<<dim3(16, 64), bt, 0, stream>>>(QKV, QKV + 1024, QKV + 2048, Ob, 3072);
        gemm_fast<false><<<dim3(8, 32), bt, 0, stream>>>(Ob, Ob, Ob, Wot, bo, bo, bo, d_out, 1024);
    } else {
        // fallback: round-1 path (needs 32 MB, proven)
        const size_t NE = (size_t)4096 * 1024;
        unsigned short* Qb = (unsigned short*)d_ws;
        unsigned short* Kb = Qb + NE;
        unsigned short* Vb = Kb + NE;
        unsigned short* Ob = Vb + NE;
        dim3 gg(8, 32);
        gemm_kernel<false, true><<<gg, bt, 0, stream>>>(q, Wq, bq, Qb);
        gemm_kernel<false, true><<<gg, bt, 0, stream>>>(k, Wk, bk, Kb);
        gemm_kernel<false, true><<<gg, bt, 0, stream>>>(v, Wv, bv, Vb);
        attn_kernel<<<dim3(16, 64), bt, 0, stream>>>(Qb, Kb, Vb, Ob, 1024);
        gemm_kernel<true, false><<<gg, bt, 0, stream>>>(Ob, Wo, bo, d_out);
    }
}

// Round 3
// 229.602 us; speedup vs baseline: 2.7673x; 1.1711x over previous
//
#include <hip/hip_runtime.h>
#include <hip/hip_bf16.h>

typedef __attribute__((ext_vector_type(4))) float f32x4;
typedef __attribute__((ext_vector_type(16))) float f32x16;
typedef __attribute__((ext_vector_type(8))) short bf16x8;
typedef __attribute__((ext_vector_type(4))) unsigned short u16x4;
typedef __attribute__((ext_vector_type(8))) unsigned short u16x8;
typedef __attribute__((ext_vector_type(2))) unsigned int u32x2;

#define MFMA16(a, b, c) __builtin_amdgcn_mfma_f32_16x16x32_bf16((a), (b), (c), 0, 0, 0)
#define MFMA32(a, b, c) __builtin_amdgcn_mfma_f32_32x32x16_bf16((a), (b), (c), 0, 0, 0)

static __device__ __forceinline__ unsigned short f2bf(float f) {
    union { float f; unsigned int u; } v; v.f = f;
    unsigned int r = v.u + 0x7FFFu + ((v.u >> 16) & 1u);  // RNE
    return (unsigned short)(r >> 16);
}
static __device__ __forceinline__ unsigned int pk2(float x, float y) {
    return (unsigned int)f2bf(x) | ((unsigned int)f2bf(y) << 16);
}

static __device__ __forceinline__ void gload_lds16(const void* g, void* l) {
    __builtin_amdgcn_global_load_lds(
        (const __attribute__((address_space(1))) void*)g,
        (__attribute__((address_space(3))) void*)l, 16, 0, 0);
}

// ---------------------------------------------------------------------------
// convert_act: fp32 -> bf16, 8 elems/thread.
// ---------------------------------------------------------------------------
__global__ __launch_bounds__(256) void convert_act(
    const float* __restrict__ q, const float* __restrict__ k,
    const float* __restrict__ v, unsigned short* __restrict__ qc,
    unsigned short* __restrict__ kc, unsigned short* __restrict__ vc) {
    const float* src = blockIdx.y == 0 ? q : (blockIdx.y == 1 ? k : v);
    unsigned short* dst = blockIdx.y == 0 ? qc : (blockIdx.y == 1 ? kc : vc);
    size_t off = ((size_t)blockIdx.x * 256 + threadIdx.x) * 8;
    f32x4 a = *(const f32x4*)&src[off];
    f32x4 b = *(const f32x4*)&src[off + 4];
    u16x8 o;
    o[0] = f2bf(a[0]); o[1] = f2bf(a[1]); o[2] = f2bf(a[2]); o[3] = f2bf(a[3]);
    o[4] = f2bf(b[0]); o[5] = f2bf(b[1]); o[6] = f2bf(b[2]); o[7] = f2bf(b[3]);
    *(u16x8*)&dst[off] = o;
}

// ---------------------------------------------------------------------------
// transpose_w: W[k][n] fp32 -> Wt[n][k] bf16. 64x64 tiles, z = matrix 0..3.
// ---------------------------------------------------------------------------
__global__ __launch_bounds__(256) void transpose_w(
    const float* __restrict__ Wq, const float* __restrict__ Wk,
    const float* __restrict__ Wv, const float* __restrict__ Wo,
    unsigned short* __restrict__ Wt_all, unsigned short* __restrict__ Wot) {
    __shared__ unsigned short T[64][65];
    const int z = blockIdx.z;
    const float* W = z == 0 ? Wq : (z == 1 ? Wk : (z == 2 ? Wv : Wo));
    unsigned short* Wt = z < 3 ? (Wt_all + (size_t)z * 1024 * 1024) : Wot;
    const int k0 = blockIdx.y * 64, n0 = blockIdx.x * 64;
    const int t = threadIdx.x;
    const int rl = t >> 4, c4 = (t & 15) * 4;
#pragma unroll
    for (int i = 0; i < 4; ++i) {
        f32x4 v = *(const f32x4*)&W[(size_t)(k0 + rl + 16 * i) * 1024 + n0 + c4];
#pragma unroll
        for (int j = 0; j < 4; ++j) T[rl + 16 * i][c4 + j] = f2bf(v[j]);
    }
    __syncthreads();
#pragma unroll
    for (int i = 0; i < 4; ++i) {
        u16x4 o;
#pragma unroll
        for (int j = 0; j < 4; ++j) o[j] = T[c4 + j][rl + 16 * i];
        *(u16x4*)&Wt[(size_t)(n0 + rl + 16 * i) * 1024 + k0 + c4] = o;
    }
}

// ---------------------------------------------------------------------------
// gemm_fast: m97 structure (global_load_lds x16, linear LDS, ds_read_b128).
// ---------------------------------------------------------------------------
template <bool OUT_BF16>
__global__ __launch_bounds__(256, 2) void gemm_fast(
    const unsigned short* __restrict__ A0, const unsigned short* __restrict__ A1,
    const unsigned short* __restrict__ A2, const unsigned short* __restrict__ Wt,
    const float* __restrict__ b0, const float* __restrict__ b1,
    const float* __restrict__ b2, void* __restrict__ Outv, int ldo) {
    __shared__ __align__(16) unsigned short As[128 * 32];
    __shared__ __align__(16) unsigned short Bs[128 * 32];

    const int t = threadIdx.x;
    const int w = t >> 6, lane = t & 63;
    const int wr = w >> 1, wc = w & 1;
    const int g = lane >> 4, r15 = lane & 15;
    const int bm = blockIdx.y * 128;
    const int bn = blockIdx.x * 128;
    const int msel = bn >> 10;
    const unsigned short* A = msel == 0 ? A0 : (msel == 1 ? A1 : A2);
    const float* bias = msel == 0 ? b0 : (msel == 1 ? b1 : b2);
    const int l4 = lane >> 2, c8 = (lane & 3) * 8;

    f32x4 acc[4][4];
#pragma unroll
    for (int m = 0; m < 4; ++m)
#pragma unroll
        for (int n = 0; n < 4; ++n) acc[m][n] = (f32x4){0.f, 0.f, 0.f, 0.f};

    for (int kt = 0; kt < 1024; kt += 32) {
        __syncthreads();
        gload_lds16(&A[(size_t)(bm + 16 * w + l4) * 1024 + kt + c8], &As[w * 512]);
        gload_lds16(&A[(size_t)(bm + 16 * (w + 4) + l4) * 1024 + kt + c8], &As[(w + 4) * 512]);
        gload_lds16(&Wt[(size_t)(bn + 16 * w + l4) * 1024 + kt + c8], &Bs[w * 512]);
        gload_lds16(&Wt[(size_t)(bn + 16 * (w + 4) + l4) * 1024 + kt + c8], &Bs[(w + 4) * 512]);
        __syncthreads();
        bf16x8 af[4], bfr[4];
#pragma unroll
        for (int m = 0; m < 4; ++m)
            af[m] = *(const bf16x8*)&As[(wr * 64 + m * 16 + r15) * 32 + g * 8];
#pragma unroll
        for (int n = 0; n < 4; ++n)
            bfr[n] = *(const bf16x8*)&Bs[(wc * 64 + n * 16 + r15) * 32 + g * 8];
#pragma unroll
        for (int m = 0; m < 4; ++m)
#pragma unroll
            for (int n = 0; n < 4; ++n)
                acc[m][n] = MFMA16(af[m], bfr[n], acc[m][n]);
    }

    float* Of = (float*)Outv;
    unsigned short* Ob = (unsigned short*)Outv;
#pragma unroll
    for (int n = 0; n < 4; ++n) {
        int col = bn + wc * 64 + n * 16 + r15;
        float bv = bias[col & 1023];
#pragma unroll
        for (int m = 0; m < 4; ++m) {
#pragma unroll
            for (int r = 0; r < 4; ++r) {
                int row = bm + wr * 64 + m * 16 + g * 4 + r;
                float val = acc[m][n][r] + bv;
                if (OUT_BF16)
                    Ob[(size_t)row * ldo + col] = f2bf(val);
                else
                    Of[(size_t)row * ldo + col] = val;
            }
        }
    }
}

// ---------------------------------------------------------------------------
// Legacy fp32-A GEMM (fallback if ws too small).
// ---------------------------------------------------------------------------
template <bool A_BF16, bool OUT_BF16>
__global__ __launch_bounds__(256, 2) void gemm_kernel(
    const void* __restrict__ Av, const float* __restrict__ W,
    const float* __restrict__ bias, void* __restrict__ Outv) {
    __shared__ __align__(16) unsigned short As[128][40];
    __shared__ __align__(16) unsigned short Bs[128][40];

    const int t = threadIdx.x;
    const int bm = blockIdx.y * 128;
    const int bn = blockIdx.x * 128;
    const int w = t >> 6, lane = t & 63;
    const int wr = w >> 1, wc = w & 1;
    const int g = lane >> 4, r15 = lane & 15;

    f32x4 acc[4][4];
#pragma unroll
    for (int m = 0; m < 4; ++m)
#pragma unroll
        for (int n = 0; n < 4; ++n) acc[m][n] = (f32x4){0.f, 0.f, 0.f, 0.f};

    const float* Af = (const float*)Av;
    const unsigned short* Ab = (const unsigned short*)Av;

    for (int kt = 0; kt < 1024; kt += 32) {
        __syncthreads();
#pragma unroll
        for (int i = 0; i < 4; ++i) {
            int row = (t >> 3) + i * 32;
            int c4 = (t & 7) * 4;
            if (A_BF16) {
                u16x4 v = *(const u16x4*)&Ab[(size_t)(bm + row) * 1024 + kt + c4];
                *(u16x4*)&As[row][c4] = v;
            } else {
                f32x4 v = *(const f32x4*)&Af[(size_t)(bm + row) * 1024 + kt + c4];
                u16x4 o;
                o[0] = f2bf(v[0]); o[1] = f2bf(v[1]);
                o[2] = f2bf(v[2]); o[3] = f2bf(v[3]);
                *(u16x4*)&As[row][c4] = o;
            }
        }
#pragma unroll
        for (int i = 0; i < 4; ++i) {
            int k = (t >> 5) + i * 8;
            int c4 = (t & 31) * 4;
            f32x4 v = *(const f32x4*)&W[(size_t)(kt + k) * 1024 + bn + c4];
#pragma unroll
            for (int j = 0; j < 4; ++j) Bs[c4 + j][k] = f2bf(v[j]);
        }
        __syncthreads();
        bf16x8 af[4], bfr[4];
#pragma unroll
        for (int m = 0; m < 4; ++m)
            af[m] = *(const bf16x8*)&As[wr * 64 + m * 16 + r15][g * 8];
#pragma unroll
        for (int n = 0; n < 4; ++n)
            bfr[n] = *(const bf16x8*)&Bs[wc * 64 + n * 16 + r15][g * 8];
#pragma unroll
        for (int m = 0; m < 4; ++m)
#pragma unroll
            for (int n = 0; n < 4; ++n)
                acc[m][n] = MFMA16(af[m], bfr[n], acc[m][n]);
    }

    float* Of = (float*)Outv;
    unsigned short* Ob = (unsigned short*)Outv;
#pragma unroll
    for (int n = 0; n < 4; ++n) {
        int col = bn + wc * 64 + n * 16 + r15;
        float bv = bias[col];
#pragma unroll
        for (int m = 0; m < 4; ++m) {
#pragma unroll
            for (int r = 0; r < 4; ++r) {
                int row = bm + wr * 64 + m * 16 + g * 4 + r;
                float val = acc[m][n][r] + bv;
                if (OUT_BF16)
                    Ob[(size_t)row * 1024 + col] = f2bf(val);
                else
                    Of[(size_t)row * 1024 + col] = val;
            }
        }
    }
}

// ---------------------------------------------------------------------------
// attn32: swapped-operand 32x32 flash attention.
// 4 waves x 32 q-rows = 128 q/block; KVBLK=64, double-buffered swizzled LDS.
// QK^T: mfma(A=K, B=Q) -> S^T (lane owns q=lane&31, keys in regs).
// PV:   mfma(A=V^T, B=P^T) -> O^T (q stays on lane; rescale lane-local).
// K/V^T LDS: stride 80 elems (160B), byte ^= (row&7)<<4 swizzle (T2).
// Grid: 512 blocks 1-D, XCD-swizzled so one (b,h)'s 8 q-blocks share an XCD.
// ---------------------------------------------------------------------------
__global__ __launch_bounds__(256, 2) void attn32_kernel(
    const unsigned short* __restrict__ Q, const unsigned short* __restrict__ K,
    const unsigned short* __restrict__ V, unsigned short* __restrict__ O, int ld) {
    __shared__ __align__(16) unsigned short Kls[2][64 * 80];
    __shared__ __align__(16) unsigned short Vls[2][64 * 80];

    const int t = threadIdx.x;
    const int w = t >> 6, lane = t & 63;
    const int q5 = lane & 31, hi = lane >> 5;

    // XCD swizzle: round-robin id%8 -> contiguous sid chunk per XCD
    const int id = blockIdx.x;
    const int sid = (id & 7) * 64 + (id >> 3);
    const int bh = sid >> 3, qb = sid & 7;
    const int b = bh >> 4, h = bh & 15;
    const int brow = b * 1024;
    const int q0 = qb * 128;

    const float c2 = 0.18033688f;  // (1/8) * log2(e)

    // ---- Q: lane holds its q-row's 64 d-values; select hi-half per k-step
    const unsigned short* Qrow = Q + (size_t)(brow + q0 + w * 32 + q5) * ld + h * 64;
    bf16x8 qreg[8];
#pragma unroll
    for (int j = 0; j < 8; ++j) qreg[j] = *(const bf16x8*)&Qrow[8 * j];
    bf16x8 qsel[4];
#pragma unroll
    for (int kk = 0; kk < 4; ++kk) qsel[kk] = hi ? qreg[2 * kk + 1] : qreg[2 * kk];

    // ---- staging roles
    const int krow = t >> 2, kpart = t & 3;      // K: row, 2x16B slots
    const int vkey = t & 63, vdc = t >> 6;       // V: key, d-chunk of 16
    const unsigned short* Kg = K + h * 64;
    const unsigned short* Vg = V + h * 64;

    u16x8 kr0, kr1, vr0, vr1;
#define STG_LOAD(KT)                                                            \
    {                                                                           \
        size_t kro = (size_t)(brow + (KT) + krow) * ld;                         \
        kr0 = *(const u16x8*)&Kg[kro + kpart * 8];                              \
        kr1 = *(const u16x8*)&Kg[kro + kpart * 8 + 32];                         \
        size_t vro = (size_t)(brow + (KT) + vkey) * ld;                         \
        vr0 = *(const u16x8*)&Vg[vro + vdc * 16];                               \
        vr1 = *(const u16x8*)&Vg[vro + vdc * 16 + 8];                           \
    }
#define STG_WRITE(BUF)                                                          \
    {                                                                           \
        char* kb_ = (char*)Kls[BUF];                                            \
        int tg_ = (krow & 7) << 4;                                              \
        *(u16x8*)(kb_ + krow * 160 + ((kpart * 16) ^ tg_)) = kr0;               \
        *(u16x8*)(kb_ + krow * 160 + (((kpart + 4) * 16) ^ tg_)) = kr1;         \
        char* vb_ = (char*)Vls[BUF];                                            \
        _Pragma("unroll") for (int j_ = 0; j_ < 8; ++j_) {                      \
            int d_ = vdc * 16 + j_;                                             \
            *(unsigned short*)(vb_ + d_ * 160 + ((vkey * 2) ^ ((d_ & 7) << 4))) \
                = vr0[j_];                                                      \
        }                                                                       \
        _Pragma("unroll") for (int j_ = 0; j_ < 8; ++j_) {                      \
            int d_ = vdc * 16 + 8 + j_;                                         \
            *(unsigned short*)(vb_ + d_ * 160 + ((vkey * 2) ^ ((d_ & 7) << 4))) \
                = vr1[j_];                                                      \
        }                                                                       \
    }

    f32x16 acc0 = {}, acc1 = {};
    float mrun = -1e30f, lrun = 0.f;

    STG_LOAD(0);
    STG_WRITE(0);
    __syncthreads();

    int cur = 0;
    for (int tile = 0; tile < 16; ++tile) {
        const bool more = tile < 15;
        if (more) STG_LOAD(tile * 64 + 64);

        // ---- QK^T: S^T tiles (keys 0..31 -> st0, 32..63 -> st1)
        char* kb = (char*)Kls[cur];
        f32x16 st0 = {}, st1 = {};
        {
            const int tg0 = (q5 & 7) << 4;
            char* kp0 = kb + q5 * 160;
            char* kp1 = kb + (q5 + 32) * 160;
#pragma unroll
            for (int kk = 0; kk < 4; ++kk) {
                int so = ((2 * kk + hi) * 16) ^ tg0;
                bf16x8 kf0 = *(const bf16x8*)(kp0 + so);
                bf16x8 kf1 = *(const bf16x8*)(kp1 + so);
                st0 = MFMA32(kf0, qsel[kk], st0);
                st1 = MFMA32(kf1, qsel[kk], st1);
            }
        }

        // ---- online softmax (lane-local rows + one cross-half exchange)
        float mloc = st0[0];
#pragma unroll
        for (int r = 1; r < 16; ++r) mloc = fmaxf(mloc, st0[r]);
#pragma unroll
        for (int r = 0; r < 16; ++r) mloc = fmaxf(mloc, st1[r]);
        mloc = fmaxf(mloc, __shfl_xor(mloc, 32));
        float mnew = fmaxf(mrun, mloc);
        float sf = exp2f((mrun - mnew) * c2);
        mrun = mnew;
        float mneg = -mrun * c2;
        float rs = 0.f;
#pragma unroll
        for (int r = 0; r < 16; ++r) {
            st0[r] = exp2f(fmaf(st0[r], c2, mneg));
            rs += st0[r];
        }
#pragma unroll
        for (int r = 0; r < 16; ++r) {
            st1[r] = exp2f(fmaf(st1[r], c2, mneg));
            rs += st1[r];
        }
        rs += __shfl_xor(rs, 32);
        lrun = lrun * sf + rs;
#pragma unroll
        for (int r = 0; r < 16; ++r) { acc0[r] *= sf; acc1[r] *= sf; }

        // ---- P^T pack + PV (O^T += V^T * P^T)
        char* vb = (char*)Vls[cur];
        const int tgv = (q5 & 7) << 4;
        char* vp0 = vb + q5 * 160;
        char* vp1 = vb + (q5 + 32) * 160;
#define PV_HALF(ST, CT)                                                         \
    _Pragma("unroll") for (int ks = 0; ks < 2; ++ks) {                          \
        unsigned int a0 = pk2(ST[8 * ks + 0], ST[8 * ks + 1]);                  \
        unsigned int a1 = pk2(ST[8 * ks + 2], ST[8 * ks + 3]);                  \
        unsigned int a2 = pk2(ST[8 * ks + 4], ST[8 * ks + 5]);                  \
        unsigned int a3 = pk2(ST[8 * ks + 6], ST[8 * ks + 7]);                  \
        unsigned int x0 = __shfl_xor(a0, 32), x1 = __shfl_xor(a1, 32);          \
        unsigned int x2 = __shfl_xor(a2, 32), x3 = __shfl_xor(a3, 32);          \
        union { unsigned int u[4]; bf16x8 v; } pfu;                             \
        pfu.u[0] = hi ? x2 : a0;                                                \
        pfu.u[1] = hi ? x3 : a1;                                                \
        pfu.u[2] = hi ? a2 : x0;                                                \
        pfu.u[3] = hi ? a3 : x1;                                                \
        int co = ((32 * (2 * (CT) + ks) + 16 * hi)) ^ tgv;                      \
        bf16x8 vf0 = *(const bf16x8*)(vp0 + co);                                \
        bf16x8 vf1 = *(const bf16x8*)(vp1 + co);                                \
        acc0 = MFMA32(vf0, pfu.v, acc0);                                        \
        acc1 = MFMA32(vf1, pfu.v, acc1);                                        \
    }
        PV_HALF(st0, 0);
        PV_HALF(st1, 1);

        if (more) STG_WRITE(cur ^ 1);
        __syncthreads();
        cur ^= 1;
    }

    // ---- epilogue: normalize, pack 4 consecutive d per reg-quad, 8B stores
    const float inv = 1.0f / lrun;
    unsigned short* Orow = O + (size_t)(brow + q0 + w * 32 + q5) * 1024 + h * 64;
#pragma unroll
    for (int k = 0; k < 4; ++k) {
        int d0 = 8 * k + 4 * hi;
        u32x2 pa, pb;
        pa[0] = pk2(acc0[4 * k + 0] * inv, acc0[4 * k + 1] * inv);
        pa[1] = pk2(acc0[4 * k + 2] * inv, acc0[4 * k + 3] * inv);
        *(u32x2*)&Orow[d0] = pa;
        pb[0] = pk2(acc1[4 * k + 0] * inv, acc1[4 * k + 1] * inv);
        pb[1] = pk2(acc1[4 * k + 2] * inv, acc1[4 * k + 3] * inv);
        *(u32x2*)&Orow[32 + d0] = pb;
    }
#undef STG_LOAD
#undef STG_WRITE
#undef PV_HALF
}

extern "C" void kernel_launch(void* const* d_in, const int* in_sizes, int n_in,
                              void* d_out, int out_size, void* d_ws, size_t ws_size,
                              hipStream_t stream) {
    const float* q  = (const float*)d_in[0];
    const float* k  = (const float*)d_in[1];
    const float* v  = (const float*)d_in[2];
    const float* Wq = (const float*)d_in[3];
    const float* bq = (const float*)d_in[4];
    const float* Wk = (const float*)d_in[5];
    const float* bk = (const float*)d_in[6];
    const float* Wv = (const float*)d_in[7];
    const float* bv = (const float*)d_in[8];
    const float* Wo = (const float*)d_in[9];
    const float* bo = (const float*)d_in[10];

    const size_t M1 = (size_t)1024 * 1024;
    const size_t NEED = 28 * M1 * sizeof(unsigned short);  // 56 MB

    dim3 bt(256, 1, 1);
    if (ws_size >= NEED) {
        unsigned short* qc  = (unsigned short*)d_ws;       // 4M elems
        unsigned short* kc  = qc + 4 * M1;
        unsigned short* vc  = kc + 4 * M1;
        unsigned short* Wt  = vc + 4 * M1;                 // 3M elems
        unsigned short* Wot = Wt + 3 * M1;                 // 1M elems
        unsigned short* QKV = Wot + M1;                    // 12M elems [4096][3072]
        unsigned short* Ob  = qc;                          // alias (qc dead by then)

        convert_act<<<dim3(2048, 3), bt, 0, stream>>>(q, k, v, qc, kc, vc);
        transpose_w<<<dim3(16, 16, 4), bt, 0, stream>>>(Wq, Wk, Wv, Wo, Wt, Wot);
        gemm_fast<true><<<dim3(24, 32), bt, 0, stream>>>(qc, kc, vc, Wt, bq, bk, bv, QKV, 3072);
        attn32_kernel<<<dim3(512), bt, 0, stream>>>(QKV, QKV + 1024, QKV + 2048, Ob, 3072);
        gemm_fast<false><<<dim3(8, 32), bt, 0, stream>>>(Ob, Ob, Ob, Wot, bo, bo, bo, d_out, 1024);
    } else {
        const size_t NE = (size_t)4096 * 1024;
        unsigned short* Qb = (unsigned short*)d_ws;
        unsigned short* Kb = Qb + NE;
        unsigned short* Vb = Kb + NE;
        unsigned short* Ob = Vb + NE;
        dim3 gg(8, 32);
        gemm_kernel<false, true><<<gg, bt, 0, stream>>>(q, Wq, bq, Qb);
        gemm_kernel<false, true><<<gg, bt, 0, stream>>>(k, Wk, bk, Kb);
        gemm_kernel<false, true><<<gg, bt, 0, stream>>>(v, Wv, bv, Vb);
        attn32_kernel<<<dim3(512), bt, 0, stream>>>(Qb, Kb, Vb, Ob, 1024);
        gemm_kernel<true, false><<<gg, bt, 0, stream>>>(Ob, Wo, bo, d_out);
    }
}

// Round 4
// 217.560 us; speedup vs baseline: 2.9205x; 1.0553x over previous
//
#include <hip/hip_runtime.h>
#include <hip/hip_bf16.h>

typedef __attribute__((ext_vector_type(4))) float f32x4;
typedef __attribute__((ext_vector_type(16))) float f32x16;
typedef __attribute__((ext_vector_type(8))) short bf16x8;
typedef __attribute__((ext_vector_type(4))) unsigned short u16x4;
typedef __attribute__((ext_vector_type(8))) unsigned short u16x8;
typedef __attribute__((ext_vector_type(2))) unsigned int u32x2;

#define MFMA16(a, b, c) __builtin_amdgcn_mfma_f32_16x16x32_bf16((a), (b), (c), 0, 0, 0)
#define MFMA32(a, b, c) __builtin_amdgcn_mfma_f32_32x32x16_bf16((a), (b), (c), 0, 0, 0)

static __device__ __forceinline__ unsigned short f2bf(float f) {
    union { float f; unsigned int u; } v; v.f = f;
    unsigned int r = v.u + 0x7FFFu + ((v.u >> 16) & 1u);  // RNE
    return (unsigned short)(r >> 16);
}
// HW packed f32->bf16 (T12 recipe; src0 -> low half)
static __device__ __forceinline__ unsigned int pk2(float x, float y) {
    unsigned int r;
    asm("v_cvt_pk_bf16_f32 %0, %1, %2" : "=v"(r) : "v"(x), "v"(y));
    return r;
}

static __device__ __forceinline__ void gload_lds16(const void* g, void* l) {
    __builtin_amdgcn_global_load_lds(
        (const __attribute__((address_space(1))) void*)g,
        (__attribute__((address_space(3))) void*)l, 16, 0, 0);
}

// ---------------------------------------------------------------------------
// convert_act: fp32 -> bf16, 8 elems/thread.
// ---------------------------------------------------------------------------
__global__ __launch_bounds__(256) void convert_act(
    const float* __restrict__ q, const float* __restrict__ k,
    const float* __restrict__ v, unsigned short* __restrict__ qc,
    unsigned short* __restrict__ kc, unsigned short* __restrict__ vc) {
    const float* src = blockIdx.y == 0 ? q : (blockIdx.y == 1 ? k : v);
    unsigned short* dst = blockIdx.y == 0 ? qc : (blockIdx.y == 1 ? kc : vc);
    size_t off = ((size_t)blockIdx.x * 256 + threadIdx.x) * 8;
    f32x4 a = *(const f32x4*)&src[off];
    f32x4 b = *(const f32x4*)&src[off + 4];
    union { unsigned int u[4]; u16x8 v; } o;
    o.u[0] = pk2(a[0], a[1]); o.u[1] = pk2(a[2], a[3]);
    o.u[2] = pk2(b[0], b[1]); o.u[3] = pk2(b[2], b[3]);
    *(u16x8*)&dst[off] = o.v;
}

// ---------------------------------------------------------------------------
// transpose_w: W[k][n] fp32 -> Wt[n][k] bf16. 64x64 tiles, z = matrix 0..3.
// ---------------------------------------------------------------------------
__global__ __launch_bounds__(256) void transpose_w(
    const float* __restrict__ Wq, const float* __restrict__ Wk,
    const float* __restrict__ Wv, const float* __restrict__ Wo,
    unsigned short* __restrict__ Wt_all, unsigned short* __restrict__ Wot) {
    __shared__ unsigned short T[64][65];
    const int z = blockIdx.z;
    const float* W = z == 0 ? Wq : (z == 1 ? Wk : (z == 2 ? Wv : Wo));
    unsigned short* Wt = z < 3 ? (Wt_all + (size_t)z * 1024 * 1024) : Wot;
    const int k0 = blockIdx.y * 64, n0 = blockIdx.x * 64;
    const int t = threadIdx.x;
    const int rl = t >> 4, c4 = (t & 15) * 4;
#pragma unroll
    for (int i = 0; i < 4; ++i) {
        f32x4 v = *(const f32x4*)&W[(size_t)(k0 + rl + 16 * i) * 1024 + n0 + c4];
#pragma unroll
        for (int j = 0; j < 4; ++j) T[rl + 16 * i][c4 + j] = f2bf(v[j]);
    }
    __syncthreads();
#pragma unroll
    for (int i = 0; i < 4; ++i) {
        u16x4 o;
#pragma unroll
        for (int j = 0; j < 4; ++j) o[j] = T[c4 + j][rl + 16 * i];
        *(u16x4*)&Wt[(size_t)(n0 + rl + 16 * i) * 1024 + k0 + c4] = o;
    }
}

// ---------------------------------------------------------------------------
// gemm_fast: m97 structure (global_load_lds x16, linear LDS, ds_read_b128).
// BN = 128 (wave 64x64, acc 4x4) or 64 (wave 64x32, acc 4x2).
// ---------------------------------------------------------------------------
template <bool OUT_BF16, int BN>
__global__ __launch_bounds__(256, 2) void gemm_fast(
    const unsigned short* __restrict__ A0, const unsigned short* __restrict__ A1,
    const unsigned short* __restrict__ A2, const unsigned short* __restrict__ Wt,
    const float* __restrict__ b0, const float* __restrict__ b1,
    const float* __restrict__ b2, void* __restrict__ Outv, int ldo) {
    constexpr int NF = BN / 32;  // n-frags per wave
    __shared__ __align__(16) unsigned short As[128 * 32];
    __shared__ __align__(16) unsigned short Bs[BN * 32];

    const int t = threadIdx.x;
    const int w = t >> 6, lane = t & 63;
    const int wr = w >> 1, wc = w & 1;
    const int g = lane >> 4, r15 = lane & 15;
    const int bm = blockIdx.y * 128;
    const int bn = blockIdx.x * BN;
    const int msel = bn >> 10;
    const unsigned short* A = msel == 0 ? A0 : (msel == 1 ? A1 : A2);
    const float* bias = msel == 0 ? b0 : (msel == 1 ? b1 : b2);
    const int l4 = lane >> 2, c8 = (lane & 3) * 8;

    f32x4 acc[4][NF];
#pragma unroll
    for (int m = 0; m < 4; ++m)
#pragma unroll
        for (int n = 0; n < NF; ++n) acc[m][n] = (f32x4){0.f, 0.f, 0.f, 0.f};

    for (int kt = 0; kt < 1024; kt += 32) {
        __syncthreads();
        gload_lds16(&A[(size_t)(bm + 16 * w + l4) * 1024 + kt + c8], &As[w * 512]);
        gload_lds16(&A[(size_t)(bm + 16 * (w + 4) + l4) * 1024 + kt + c8], &As[(w + 4) * 512]);
        if (BN == 128) {
            gload_lds16(&Wt[(size_t)(bn + 16 * w + l4) * 1024 + kt + c8], &Bs[w * 512]);
            gload_lds16(&Wt[(size_t)(bn + 16 * (w + 4) + l4) * 1024 + kt + c8],
                        &Bs[(w + 4) * 512 % (BN * 32)]);
        } else {
            gload_lds16(&Wt[(size_t)(bn + 16 * w + l4) * 1024 + kt + c8], &Bs[w * 512]);
        }
        __syncthreads();
        bf16x8 af[4], bfr[NF];
#pragma unroll
        for (int m = 0; m < 4; ++m)
            af[m] = *(const bf16x8*)&As[(wr * 64 + m * 16 + r15) * 32 + g * 8];
#pragma unroll
        for (int n = 0; n < NF; ++n)
            bfr[n] = *(const bf16x8*)&Bs[(wc * (BN / 2) + n * 16 + r15) * 32 + g * 8];
#pragma unroll
        for (int m = 0; m < 4; ++m)
#pragma unroll
            for (int n = 0; n < NF; ++n)
                acc[m][n] = MFMA16(af[m], bfr[n], acc[m][n]);
    }

    float* Of = (float*)Outv;
    unsigned short* Ob = (unsigned short*)Outv;
#pragma unroll
    for (int n = 0; n < NF; ++n) {
        int col = bn + wc * (BN / 2) + n * 16 + r15;
        float bv = bias[col & 1023];
#pragma unroll
        for (int m = 0; m < 4; ++m) {
#pragma unroll
            for (int r = 0; r < 4; ++r) {
                int row = bm + wr * 64 + m * 16 + g * 4 + r;
                float val = acc[m][n][r] + bv;
                if (OUT_BF16)
                    Ob[(size_t)row * ldo + col] = f2bf(val);
                else
                    Of[(size_t)row * ldo + col] = val;
            }
        }
    }
}

// ---------------------------------------------------------------------------
// Legacy fp32-A GEMM (fallback if ws too small).
// ---------------------------------------------------------------------------
template <bool A_BF16, bool OUT_BF16>
__global__ __launch_bounds__(256, 2) void gemm_kernel(
    const void* __restrict__ Av, const float* __restrict__ W,
    const float* __restrict__ bias, void* __restrict__ Outv) {
    __shared__ __align__(16) unsigned short As[128][40];
    __shared__ __align__(16) unsigned short Bs[128][40];

    const int t = threadIdx.x;
    const int bm = blockIdx.y * 128;
    const int bn = blockIdx.x * 128;
    const int w = t >> 6, lane = t & 63;
    const int wr = w >> 1, wc = w & 1;
    const int g = lane >> 4, r15 = lane & 15;

    f32x4 acc[4][4];
#pragma unroll
    for (int m = 0; m < 4; ++m)
#pragma unroll
        for (int n = 0; n < 4; ++n) acc[m][n] = (f32x4){0.f, 0.f, 0.f, 0.f};

    const float* Af = (const float*)Av;
    const unsigned short* Ab = (const unsigned short*)Av;

    for (int kt = 0; kt < 1024; kt += 32) {
        __syncthreads();
#pragma unroll
        for (int i = 0; i < 4; ++i) {
            int row = (t >> 3) + i * 32;
            int c4 = (t & 7) * 4;
            if (A_BF16) {
                u16x4 v = *(const u16x4*)&Ab[(size_t)(bm + row) * 1024 + kt + c4];
                *(u16x4*)&As[row][c4] = v;
            } else {
                f32x4 v = *(const f32x4*)&Af[(size_t)(bm + row) * 1024 + kt + c4];
                u16x4 o;
                o[0] = f2bf(v[0]); o[1] = f2bf(v[1]);
                o[2] = f2bf(v[2]); o[3] = f2bf(v[3]);
                *(u16x4*)&As[row][c4] = o;
            }
        }
#pragma unroll
        for (int i = 0; i < 4; ++i) {
            int k = (t >> 5) + i * 8;
            int c4 = (t & 31) * 4;
            f32x4 v = *(const f32x4*)&W[(size_t)(kt + k) * 1024 + bn + c4];
#pragma unroll
            for (int j = 0; j < 4; ++j) Bs[c4 + j][k] = f2bf(v[j]);
        }
        __syncthreads();
        bf16x8 af[4], bfr[4];
#pragma unroll
        for (int m = 0; m < 4; ++m)
            af[m] = *(const bf16x8*)&As[wr * 64 + m * 16 + r15][g * 8];
#pragma unroll
        for (int n = 0; n < 4; ++n)
            bfr[n] = *(const bf16x8*)&Bs[wc * 64 + n * 16 + r15][g * 8];
#pragma unroll
        for (int m = 0; m < 4; ++m)
#pragma unroll
            for (int n = 0; n < 4; ++n)
                acc[m][n] = MFMA16(af[m], bfr[n], acc[m][n]);
    }

    float* Of = (float*)Outv;
    unsigned short* Ob = (unsigned short*)Outv;
#pragma unroll
    for (int n = 0; n < 4; ++n) {
        int col = bn + wc * 64 + n * 16 + r15;
        float bv = bias[col];
#pragma unroll
        for (int m = 0; m < 4; ++m) {
#pragma unroll
            for (int r = 0; r < 4; ++r) {
                int row = bm + wr * 64 + m * 16 + g * 4 + r;
                float val = acc[m][n][r] + bv;
                if (OUT_BF16)
                    Ob[(size_t)row * 1024 + col] = f2bf(val);
                else
                    Of[(size_t)row * 1024 + col] = val;
            }
        }
    }
}

// ---------------------------------------------------------------------------
// attn32: swapped-operand 32x32 flash attention.
// 4 waves x 32 q-rows = 128 q/block; KVBLK=64, double-buffered swizzled LDS.
// QK^T: mfma(A=K, B=Q) -> S^T (lane owns q=lane&31, keys in regs).
// PV:   mfma(A=V^T, B=P^T) -> O^T (q stays on lane; rescale lane-local).
// Round 4: cvt_pk asm pack, defer-max (THR=64 raw = 8 exp-units),
// pair-packed b32 V staging, s_setprio around MFMA clusters.
// ---------------------------------------------------------------------------
__global__ __launch_bounds__(256, 2) void attn32_kernel(
    const unsigned short* __restrict__ Q, const unsigned short* __restrict__ K,
    const unsigned short* __restrict__ V, unsigned short* __restrict__ O, int ld) {
    __shared__ __align__(16) unsigned short Kls[2][64 * 80];
    __shared__ __align__(16) unsigned short Vls[2][64 * 80];

    const int t = threadIdx.x;
    const int w = t >> 6, lane = t & 63;
    const int q5 = lane & 31, hi = lane >> 5;

    const int id = blockIdx.x;
    const int sid = (id & 7) * 64 + (id >> 3);
    const int bh = sid >> 3, qb = sid & 7;
    const int b = bh >> 4, h = bh & 15;
    const int brow = b * 1024;
    const int q0 = qb * 128;

    const float c2 = 0.18033688f;  // (1/8) * log2(e)

    const unsigned short* Qrow = Q + (size_t)(brow + q0 + w * 32 + q5) * ld + h * 64;
    bf16x8 qreg[8];
#pragma unroll
    for (int j = 0; j < 8; ++j) qreg[j] = *(const bf16x8*)&Qrow[8 * j];
    bf16x8 qsel[4];
#pragma unroll
    for (int kk = 0; kk < 4; ++kk) qsel[kk] = hi ? qreg[2 * kk + 1] : qreg[2 * kk];

    // staging roles: K by (row, 16B slot); V by (key-pair, d-chunk of 8)
    const int krow = t >> 2, kpart = t & 3;
    const int vp = t & 31, vdc = t >> 5;  // keys 2vp,2vp+1; d chunk 8*vdc
    const unsigned short* Kg = K + h * 64;
    const unsigned short* Vg = V + h * 64;

    u16x8 kr0, kr1, vr0, vr1;
#define STG_LOAD(KT)                                                            \
    {                                                                           \
        size_t kro = (size_t)(brow + (KT) + krow) * ld;                         \
        kr0 = *(const u16x8*)&Kg[kro + kpart * 8];                              \
        kr1 = *(const u16x8*)&Kg[kro + kpart * 8 + 32];                         \
        size_t vro = (size_t)(brow + (KT) + 2 * vp) * ld;                       \
        vr0 = *(const u16x8*)&Vg[vro + vdc * 8];                                \
        vr1 = *(const u16x8*)&Vg[vro + ld + vdc * 8];                           \
    }
#define STG_WRITE(BUF)                                                          \
    {                                                                           \
        char* kb_ = (char*)Kls[BUF];                                            \
        int tg_ = (krow & 7) << 4;                                              \
        *(u16x8*)(kb_ + krow * 160 + ((kpart * 16) ^ tg_)) = kr0;               \
        *(u16x8*)(kb_ + krow * 160 + (((kpart + 4) * 16) ^ tg_)) = kr1;         \
        char* vb_ = (char*)Vls[BUF];                                            \
        _Pragma("unroll") for (int j_ = 0; j_ < 8; ++j_) {                      \
            int d_ = vdc * 8 + j_;                                              \
            unsigned int pk_ = (unsigned int)(unsigned short)vr0[j_] |          \
                               ((unsigned int)(unsigned short)vr1[j_] << 16);   \
            *(unsigned int*)(vb_ + d_ * 160 + ((vp * 4) ^ ((d_ & 7) << 4)))     \
                = pk_;                                                          \
        }                                                                       \
    }

    f32x16 acc0 = {}, acc1 = {};
    float mrun = -1e30f, lrun = 0.f;

    STG_LOAD(0);
    STG_WRITE(0);
    __syncthreads();

    int cur = 0;
    for (int tile = 0; tile < 16; ++tile) {
        const bool more = tile < 15;
        if (more) STG_LOAD(tile * 64 + 64);

        // ---- QK^T
        char* kb = (char*)Kls[cur];
        f32x16 st0 = {}, st1 = {};
        {
            const int tg0 = (q5 & 7) << 4;
            char* kp0 = kb + q5 * 160;
            char* kp1 = kb + (q5 + 32) * 160;
            __builtin_amdgcn_s_setprio(1);
#pragma unroll
            for (int kk = 0; kk < 4; ++kk) {
                int so = ((2 * kk + hi) * 16) ^ tg0;
                bf16x8 kf0 = *(const bf16x8*)(kp0 + so);
                bf16x8 kf1 = *(const bf16x8*)(kp1 + so);
                st0 = MFMA32(kf0, qsel[kk], st0);
                st1 = MFMA32(kf1, qsel[kk], st1);
            }
            __builtin_amdgcn_s_setprio(0);
        }

        // ---- online softmax with defer-max (T13)
        float mloc = fmaxf(st0[0], st0[1]);
#pragma unroll
        for (int r = 2; r < 16; ++r) mloc = fmaxf(mloc, st0[r]);
#pragma unroll
        for (int r = 0; r < 16; ++r) mloc = fmaxf(mloc, st1[r]);
        mloc = fmaxf(mloc, __shfl_xor(mloc, 32));
        if (!__all(mloc - mrun <= 64.f)) {
            float mnew = fmaxf(mrun, mloc);
            float sf = exp2f((mrun - mnew) * c2);
            mrun = mnew;
            lrun *= sf;
#pragma unroll
            for (int r = 0; r < 16; ++r) { acc0[r] *= sf; acc1[r] *= sf; }
        }
        float mneg = -mrun * c2;
        float rs = 0.f;
#pragma unroll
        for (int r = 0; r < 16; ++r) {
            st0[r] = exp2f(fmaf(st0[r], c2, mneg));
            rs += st0[r];
        }
#pragma unroll
        for (int r = 0; r < 16; ++r) {
            st1[r] = exp2f(fmaf(st1[r], c2, mneg));
            rs += st1[r];
        }
        rs += __shfl_xor(rs, 32);
        lrun += rs;

        // ---- P^T pack (cvt_pk) + PV (O^T += V^T * P^T)
        char* vb = (char*)Vls[cur];
        const int tgv = (q5 & 7) << 4;
        char* vp0 = vb + q5 * 160;
        char* vp1 = vb + (q5 + 32) * 160;
        __builtin_amdgcn_s_setprio(1);
#define PV_HALF(ST, CT)                                                         \
    _Pragma("unroll") for (int ks = 0; ks < 2; ++ks) {                          \
        unsigned int a0 = pk2(ST[8 * ks + 0], ST[8 * ks + 1]);                  \
        unsigned int a1 = pk2(ST[8 * ks + 2], ST[8 * ks + 3]);                  \
        unsigned int a2 = pk2(ST[8 * ks + 4], ST[8 * ks + 5]);                  \
        unsigned int a3 = pk2(ST[8 * ks + 6], ST[8 * ks + 7]);                  \
        unsigned int x0 = __shfl_xor(a0, 32), x1 = __shfl_xor(a1, 32);          \
        unsigned int x2 = __shfl_xor(a2, 32), x3 = __shfl_xor(a3, 32);          \
        union { unsigned int u[4]; bf16x8 v; } pfu;                             \
        pfu.u[0] = hi ? x2 : a0;                                                \
        pfu.u[1] = hi ? x3 : a1;                                                \
        pfu.u[2] = hi ? a2 : x0;                                                \
        pfu.u[3] = hi ? a3 : x1;                                                \
        int co = ((32 * (2 * (CT) + ks) + 16 * hi)) ^ tgv;                      \
        bf16x8 vf0 = *(const bf16x8*)(vp0 + co);                                \
        bf16x8 vf1 = *(const bf16x8*)(vp1 + co);                                \
        acc0 = MFMA32(vf0, pfu.v, acc0);                                        \
        acc1 = MFMA32(vf1, pfu.v, acc1);                                        \
    }
        PV_HALF(st0, 0);
        PV_HALF(st1, 1);
        __builtin_amdgcn_s_setprio(0);

        if (more) STG_WRITE(cur ^ 1);
        __syncthreads();
        cur ^= 1;
    }

    // ---- epilogue
    const float inv = 1.0f / lrun;
    unsigned short* Orow = O + (size_t)(brow + q0 + w * 32 + q5) * 1024 + h * 64;
#pragma unroll
    for (int k = 0; k < 4; ++k) {
        int d0 = 8 * k + 4 * hi;
        u32x2 pa, pb;
        pa[0] = pk2(acc0[4 * k + 0] * inv, acc0[4 * k + 1] * inv);
        pa[1] = pk2(acc0[4 * k + 2] * inv, acc0[4 * k + 3] * inv);
        *(u32x2*)&Orow[d0] = pa;
        pb[0] = pk2(acc1[4 * k + 0] * inv, acc1[4 * k + 1] * inv);
        pb[1] = pk2(acc1[4 * k + 2] * inv, acc1[4 * k + 3] * inv);
        *(u32x2*)&Orow[32 + d0] = pb;
    }
#undef STG_LOAD
#undef STG_WRITE
#undef PV_HALF
}

extern "C" void kernel_launch(void* const* d_in, const int* in_sizes, int n_in,
                              void* d_out, int out_size, void* d_ws, size_t ws_size,
                              hipStream_t stream) {
    const float* q  = (const float*)d_in[0];
    const float* k  = (const float*)d_in[1];
    const float* v  = (const float*)d_in[2];
    const float* Wq = (const float*)d_in[3];
    const float* bq = (const float*)d_in[4];
    const float* Wk = (const float*)d_in[5];
    const float* bk = (const float*)d_in[6];
    const float* Wv = (const float*)d_in[7];
    const float* bv = (const float*)d_in[8];
    const float* Wo = (const float*)d_in[9];
    const float* bo = (const float*)d_in[10];

    const size_t M1 = (size_t)1024 * 1024;
    const size_t NEED = 28 * M1 * sizeof(unsigned short);  // 56 MB

    dim3 bt(256, 1, 1);
    if (ws_size >= NEED) {
        unsigned short* qc  = (unsigned short*)d_ws;       // 4M elems
        unsigned short* kc  = qc + 4 * M1;
        unsigned short* vc  = kc + 4 * M1;
        unsigned short* Wt  = vc + 4 * M1;                 // 3M elems
        unsigned short* Wot = Wt + 3 * M1;                 // 1M elems
        unsigned short* QKV = Wot + M1;                    // 12M elems [4096][3072]
        unsigned short* Ob  = qc;                          // alias (qc dead by then)

        convert_act<<<dim3(2048, 3), bt, 0, stream>>>(q, k, v, qc, kc, vc);
        transpose_w<<<dim3(16, 16, 4), bt, 0, stream>>>(Wq, Wk, Wv, Wo, Wt, Wot);
        gemm_fast<true, 128><<<dim3(24, 32), bt, 0, stream>>>(qc, kc, vc, Wt, bq, bk, bv, QKV, 3072);
        attn32_kernel<<<dim3(512), bt, 0, stream>>>(QKV, QKV + 1024, QKV + 2048, Ob, 3072);
        gemm_fast<false, 64><<<dim3(16, 32), bt, 0, stream>>>(Ob, Ob, Ob, Wot, bo, bo, bo, d_out, 1024);
    } else {
        const size_t NE = (size_t)4096 * 1024;
        unsigned short* Qb = (unsigned short*)d_ws;
        unsigned short* Kb = Qb + NE;
        unsigned short* Vb = Kb + NE;
        unsigned short* Ob = Vb + NE;
        dim3 gg(8, 32);
        gemm_kernel<false, true><<<gg, bt, 0, stream>>>(q, Wq, bq, Qb);
        gemm_kernel<false, true><<<gg, bt, 0, stream>>>(k, Wk, bk, Kb);
        gemm_kernel<false, true><<<gg, bt, 0, stream>>>(v, Wv, bv, Vb);
        attn32_kernel<<<dim3(512), bt, 0, stream>>>(Qb, Kb, Vb, Ob, 1024);
        gemm_kernel<true, false><<<gg, bt, 0, stream>>>(Ob, Wo, bo, d_out);
    }
}